// Round 7
// baseline (195.430 us; speedup 1.0000x reference)
//
#include <hip/hip_runtime.h>
#include <stdint.h>

#define NA 98304
#define NT 1024
#define NC 21
#define ACH 96           // anchor chunks of 1024 (4 anchors per thread)
#define TCH 16           // target chunks of 64

// ws layout:
//   [0]   double cls_sum
//   [8]   int    n_pos
//   [12]  int    done_cnt
//   [16]         u64 tkeys[NT]    (8 KB)
//   [16+8192]    u64 akeys[NA]    (768 KB)
// memset covers [0, 16 + 8192 + NA*8)

__device__ __forceinline__ void iou_iu(const float4 A, const float arA,
                                       const float4 tb, const float sa,
                                       float& inter, float& uni)
{
    const float lx = fmaxf(A.x, tb.x);
    const float ly = fmaxf(A.y, tb.y);
    const float rx = fminf(A.z, tb.z);
    const float ry = fminf(A.w, tb.w);
    const float w  = fmaxf(rx - lx, 0.f);
    const float h  = fmaxf(ry - ly, 0.f);
    inter = w * h;
    uni   = (arA + sa) - inter;
}

__global__ __launch_bounds__(256) void k_match(
    const float4* __restrict__ anchors,
    const float4* __restrict__ tboxes,
    unsigned long long* __restrict__ akeys,
    unsigned long long* __restrict__ tkeys)
{
    __shared__ float4 s_t[64];
    __shared__ unsigned long long s_tk[64];   // per-block target-side winners

    const int tid   = threadIdx.x;
    const int tbase = blockIdx.y * 64;
    const int a0    = blockIdx.x * 1024 + tid;   // anchors a0, +256, +512, +768

    if (tid < 64) {
        s_t[tid]  = tboxes[tbase + tid];
        s_tk[tid] = 0ull;
    }
    const float4 A0 = anchors[a0];
    const float4 A1 = anchors[a0 + 256];
    const float4 A2 = anchors[a0 + 512];
    const float4 A3 = anchors[a0 + 768];
    __syncthreads();

    const float ar0 = (A0.z - A0.x) * (A0.w - A0.y);
    const float ar1 = (A1.z - A1.x) * (A1.w - A1.y);
    const float ar2 = (A2.z - A2.x) * (A2.w - A2.y);
    const float ar3 = (A3.z - A3.x) * (A3.w - A3.y);

    // Anchor-side best tracked ONLY among iou>=0.5 pairs (below-threshold
    // pairs can't matter: label would be -1). Rounded-fp32-iou strict '>' in
    // ascending t == reference fp32 argmax first-index semantics.
    float b0 = 0.f, b1 = 0.f, b2 = 0.f, b3 = 0.f;
    int   i0 = -1,  i1 = -1,  i2 = -1,  i3 = -1;

    #pragma unroll 4
    for (int t = 0; t < 64; ++t) {
        const float4 tb = s_t[t];          // one broadcast b128 feeds 4 anchors
        const float sa = (tb.z - tb.x) * (tb.w - tb.y);

        float in0, un0, in1, un1, in2, un2, in3, un3;
        iou_iu(A0, ar0, tb, sa, in0, un0);
        iou_iu(A1, ar1, tb, sa, in1, un1);
        iou_iu(A2, ar2, tb, sa, in2, un2);
        iou_iu(A3, ar3, tb, sa, in3, un3);

        const bool h0 = (in0 + in0 >= un0);
        const bool h1 = (in1 + in1 >= un1);
        const bool h2 = (in2 + in2 >= un2);
        const bool h3 = (in3 + in3 >= un3);

        // single rare branch for all 4 anchors (iou>=0.5 density ~0.02%)
        if (__builtin_expect((h0 | h1) | (h2 | h3), 0)) {
            if (h0) {
                const float iou = in0 / un0;
                if (iou > b0) { b0 = iou; i0 = t; }
                atomicMax(&s_tk[t],
                          ((unsigned long long)__float_as_uint(iou) << 32) |
                          (unsigned long long)(0xFFFFFFFFu - (unsigned int)a0));
            }
            if (h1) {
                const float iou = in1 / un1;
                if (iou > b1) { b1 = iou; i1 = t; }
                atomicMax(&s_tk[t],
                          ((unsigned long long)__float_as_uint(iou) << 32) |
                          (unsigned long long)(0xFFFFFFFFu - (unsigned int)(a0 + 256)));
            }
            if (h2) {
                const float iou = in2 / un2;
                if (iou > b2) { b2 = iou; i2 = t; }
                atomicMax(&s_tk[t],
                          ((unsigned long long)__float_as_uint(iou) << 32) |
                          (unsigned long long)(0xFFFFFFFFu - (unsigned int)(a0 + 512)));
            }
            if (h3) {
                const float iou = in3 / un3;
                if (iou > b3) { b3 = iou; i3 = t; }
                atomicMax(&s_tk[t],
                          ((unsigned long long)__float_as_uint(iou) << 32) |
                          (unsigned long long)(0xFFFFFFFFu - (unsigned int)(a0 + 768)));
            }
        }
    }

    if (i0 >= 0)
        atomicMax(&akeys[a0],
                  ((unsigned long long)__float_as_uint(b0) << 32) |
                  (unsigned long long)(0xFFFFFFFFu - (unsigned int)(tbase + i0)));
    if (i1 >= 0)
        atomicMax(&akeys[a0 + 256],
                  ((unsigned long long)__float_as_uint(b1) << 32) |
                  (unsigned long long)(0xFFFFFFFFu - (unsigned int)(tbase + i1)));
    if (i2 >= 0)
        atomicMax(&akeys[a0 + 512],
                  ((unsigned long long)__float_as_uint(b2) << 32) |
                  (unsigned long long)(0xFFFFFFFFu - (unsigned int)(tbase + i2)));
    if (i3 >= 0)
        atomicMax(&akeys[a0 + 768],
                  ((unsigned long long)__float_as_uint(b3) << 32) |
                  (unsigned long long)(0xFFFFFFFFu - (unsigned int)(tbase + i3)));

    __syncthreads();
    if (tid < 64) {
        const unsigned long long tk = s_tk[tid];
        if (tk != 0ull) atomicMax(&tkeys[tbase + tid], tk);
    }
}

__device__ __forceinline__ float smooth_l1(float d) {
    const float ad = fabsf(d);
    return (ad < 1.f) ? 0.5f * d * d : ad - 0.5f;
}

// one block per 64 anchors (1536 blocks -> 6/CU); last block does reg + combine
__global__ __launch_bounds__(256) void k_cls_final(
    const float* __restrict__ preds,
    const int* __restrict__ tlabels,
    const float4* __restrict__ anchors,
    const float4* __restrict__ tboxes,
    const float4* __restrict__ bpreds,
    const unsigned long long* __restrict__ akeys,
    const unsigned long long* __restrict__ tkeys,
    double* __restrict__ cls_sum,
    int* __restrict__ n_pos,
    int* __restrict__ done_cnt,
    float* __restrict__ out)
{
    __shared__ int s_lab[64];
    __shared__ float s_red[8];
    __shared__ int s_flag;
    __shared__ double s_cls;
    __shared__ int s_np;

    const int tid = threadIdx.x;
    const int blk = blockIdx.x;

    if (tid < 64) {   // exactly wave 0: full-wave ballot is safe
        const unsigned long long akey = akeys[blk * 64 + tid];
        int lab = -1;
        if (akey != 0ull) {
            const unsigned int t = 0xFFFFFFFFu - (unsigned int)(akey & 0xFFFFFFFFull);
            lab = tlabels[t];
        }
        s_lab[tid] = lab;
        const unsigned long long bal = __ballot(akey != 0ull);
        if (tid == 0) atomicAdd(n_pos, (int)__popcll(bal));
    }
    __syncthreads();

    // focal loss over this block's 64 anchors x 21 classes (contiguous, coalesced)
    float acc = 0.f;
    const int base = blk * (64 * NC);
    for (int e = tid; e < 64 * NC; e += 256) {
        const int al = e / NC;            // magic-mul div
        const int c  = e - al * NC;
        const float x  = preds[base + e];
        const float t  = (s_lab[al] == c) ? 1.f : 0.f;
        const float ax = fabsf(x);
        const float u  = __expf(-ax);
        const float ce = fmaxf(x, 0.f) - x * t + __logf(1.f + u);
        const float p  = (x >= 0.f ? 1.f : u) / (1.f + u);
        const float pt = p * t + (1.f - p) * (1.f - t);
        const float at = 0.25f * t + 0.75f * (1.f - t);
        const float om = 1.f - pt;
        acc += at * om * om * ce;
    }
    for (int o = 32; o > 0; o >>= 1) acc += __shfl_down(acc, o);
    const int lane = tid & 63, wid = tid >> 6;
    if (lane == 0) s_red[wid] = acc;
    __syncthreads();
    if (tid == 0) {
        atomicAdd(cls_sum, (double)(s_red[0] + s_red[1] + s_red[2] + s_red[3]));
        __threadfence();
        const int old = atomicAdd(done_cnt, 1);
        s_flag = (old == (int)gridDim.x - 1);
    }
    __syncthreads();
    if (!s_flag) return;

    // ---- last block: regression loss + final combine ----
    if (tid == 0) {
        s_cls = atomicAdd(cls_sum, 0.0);  // coherent device-scope read
        s_np  = atomicAdd(n_pos, 0);
    }
    __syncthreads();

    float s = 0.f, m = 0.f;
    #pragma unroll
    for (int j = 0; j < 4; ++j) {
        const int t = tid + 256 * j;
        const unsigned long long key = tkeys[t];
        if (key != 0ull) {
            const unsigned int ga = 0xFFFFFFFFu - (unsigned int)(key & 0xFFFFFFFFull);
            const float4 tb = tboxes[t];
            const float4 abx = anchors[ga];
            const float4 pb = bpreds[ga];
            const float bw = tb.z - tb.x, bh = tb.w - tb.y;
            const float bcx = tb.x + 0.5f * bw, bcy = tb.y + 0.5f * bh;
            const float aw = abx.z - abx.x, ah = abx.w - abx.y;
            const float acx = abx.x + 0.5f * aw, acy = abx.y + 0.5f * ah;
            const float tx = (bcx - acx) / aw;
            const float ty = (bcy - acy) / ah;
            const float tw = logf(fmaxf(bw, 1e-8f) / aw);
            const float th = logf(fmaxf(bh, 1e-8f) / ah);
            s = smooth_l1(pb.x - tx) + smooth_l1(pb.y - ty) +
                smooth_l1(pb.z - tw) + smooth_l1(pb.w - th);
            m = 1.f;
        }
    }
    for (int o = 32; o > 0; o >>= 1) {
        s += __shfl_down(s, o);
        m += __shfl_down(m, o);
    }
    __syncthreads();          // s_red reuse
    if (lane == 0) { s_red[wid] = s; s_red[4 + wid] = m; }
    __syncthreads();
    if (tid == 0) {
        const float rs = s_red[0] + s_red[1] + s_red[2] + s_red[3];
        const float rm = s_red[4] + s_red[5] + s_red[6] + s_red[7];
        const float cls = (float)(s_cls / (double)s_np);
        const float reg = rs / (fmaxf(rm, 1.f) * 4.f);
        out[0] = cls + reg;
        out[1] = cls;
        out[2] = reg;
    }
}

extern "C" void kernel_launch(void* const* d_in, const int* in_sizes, int n_in,
                              void* d_out, int out_size, void* d_ws, size_t ws_size,
                              hipStream_t stream) {
    const float*  cls_preds = (const float*)d_in[0];
    const float4* bpreds    = (const float4*)d_in[1];
    const float4* anchors   = (const float4*)d_in[2];
    const float4* tboxes    = (const float4*)d_in[3];
    const int*    tlabels   = (const int*)d_in[4];

    char* ws = (char*)d_ws;
    double* cls_sum = (double*)(ws + 0);
    int*    n_pos   = (int*)(ws + 8);
    int*    done    = (int*)(ws + 12);
    unsigned long long* tkeys = (unsigned long long*)(ws + 16);
    unsigned long long* akeys = (unsigned long long*)(ws + 16 + NT * 8);

    hipMemsetAsync(d_ws, 0, 16 + NT * 8 + NA * 8, stream);

    k_match<<<dim3(ACH, TCH), 256, 0, stream>>>(anchors, tboxes, akeys, tkeys);
    k_cls_final<<<NA / 64, 256, 0, stream>>>(cls_preds, tlabels, anchors, tboxes,
                                             bpreds, akeys, tkeys,
                                             cls_sum, n_pos, done, (float*)d_out);
}

// Round 8
// 169.929 us; speedup vs baseline: 1.1501x; 1.1501x over previous
//
#include <hip/hip_runtime.h>
#include <stdint.h>

#define NA 98304
#define NT 1024
#define NC 21
#define ACH 96           // anchor chunks of 1024 (4 anchors per thread)
#define TCH 16           // target chunks of 64
#define HI_MIN 0xBF000000u   // min high-word of a valid key (iou>=0.5, bias bit set)

// ws layout:
//   [0]    float cls_sum
//   [4]    int   n_pos
//   [8]    int   done_global
//   [12]   int   done_ac[96]
//   [1024]      u64 tkeys[NT]   (NOT zeroed: poison-proof key encoding)
//   [9216]      u64 akeys[NA]   (NOT zeroed)
// memset covers only [0, 512)

__device__ __forceinline__ void iou_iu(const float4 A, const float arA,
                                       const float4 tb, const float sa,
                                       float& inter, float& uni)
{
    const float lx = fmaxf(A.x, tb.x);
    const float ly = fmaxf(A.y, tb.y);
    const float rx = fminf(A.z, tb.z);
    const float ry = fminf(A.w, tb.w);
    const float w  = fmaxf(rx - lx, 0.f);
    const float h  = fmaxf(ry - ly, 0.f);
    inter = w * h;
    uni   = (arA + sa) - inter;
}

__device__ __forceinline__ unsigned long long mk_key(float iou, unsigned int idx) {
    // bias bit guarantees valid keys beat 0xAA-poison AND zero under unsigned max;
    // iou ordering preserved; low word 0xFFFFFFFF-idx -> smaller index wins ties.
    return ((unsigned long long)(__float_as_uint(iou) | 0x80000000u) << 32) |
           (unsigned long long)(0xFFFFFFFFu - idx);
}

__device__ __forceinline__ float smooth_l1(float d) {
    const float ad = fabsf(d);
    return (ad < 1.f) ? 0.5f * d * d : ad - 0.5f;
}

__global__ __launch_bounds__(256) void k_fused(
    const float* __restrict__ preds,
    const int* __restrict__ tlabels,
    const float4* __restrict__ anchors,
    const float4* __restrict__ tboxes,
    const float4* __restrict__ bpreds,
    unsigned long long* __restrict__ akeys,
    unsigned long long* __restrict__ tkeys,
    float* __restrict__ cls_sum,
    int* __restrict__ n_pos,
    int* __restrict__ done_global,
    int* __restrict__ done_ac,
    float* __restrict__ out)
{
    __shared__ float4 s_t[64];
    __shared__ unsigned long long s_tk[64];
    __shared__ int   s_lab[1024];      // completer phase: labels for 1024 anchors
    __shared__ float s_red[8];
    __shared__ int   s_cnt[4];
    __shared__ int   s_role, s_fin;
    __shared__ float s_clsf;
    __shared__ int   s_npf;

    const int tid   = threadIdx.x;
    const int ac    = blockIdx.x;
    const int tbase = blockIdx.y * 64;
    const int a0    = ac * 1024 + tid;   // anchors a0, +256, +512, +768

    if (tid < 64) {
        s_t[tid]  = tboxes[tbase + tid];
        s_tk[tid] = 0ull;
    }
    const float4 A0 = anchors[a0];
    const float4 A1 = anchors[a0 + 256];
    const float4 A2 = anchors[a0 + 512];
    const float4 A3 = anchors[a0 + 768];
    __syncthreads();

    const float ar0 = (A0.z - A0.x) * (A0.w - A0.y);
    const float ar1 = (A1.z - A1.x) * (A1.w - A1.y);
    const float ar2 = (A2.z - A2.x) * (A2.w - A2.y);
    const float ar3 = (A3.z - A3.x) * (A3.w - A3.y);

    float b0 = 0.f, b1 = 0.f, b2 = 0.f, b3 = 0.f;
    int   i0 = -1,  i1 = -1,  i2 = -1,  i3 = -1;

    #pragma unroll 4
    for (int t = 0; t < 64; ++t) {
        const float4 tb = s_t[t];          // one broadcast b128 feeds 4 anchors
        const float sa = (tb.z - tb.x) * (tb.w - tb.y);

        float in0, un0, in1, un1, in2, un2, in3, un3;
        iou_iu(A0, ar0, tb, sa, in0, un0);
        iou_iu(A1, ar1, tb, sa, in1, un1);
        iou_iu(A2, ar2, tb, sa, in2, un2);
        iou_iu(A3, ar3, tb, sa, in3, un3);

        const bool h0 = (in0 + in0 >= un0);
        const bool h1 = (in1 + in1 >= un1);
        const bool h2 = (in2 + in2 >= un2);
        const bool h3 = (in3 + in3 >= un3);

        if (__builtin_expect((h0 | h1) | (h2 | h3), 0)) {
            if (h0) { const float iou = in0 / un0;
                if (iou > b0) { b0 = iou; i0 = t; }
                atomicMax(&s_tk[t], mk_key(iou, (unsigned int)a0)); }
            if (h1) { const float iou = in1 / un1;
                if (iou > b1) { b1 = iou; i1 = t; }
                atomicMax(&s_tk[t], mk_key(iou, (unsigned int)(a0 + 256))); }
            if (h2) { const float iou = in2 / un2;
                if (iou > b2) { b2 = iou; i2 = t; }
                atomicMax(&s_tk[t], mk_key(iou, (unsigned int)(a0 + 512))); }
            if (h3) { const float iou = in3 / un3;
                if (iou > b3) { b3 = iou; i3 = t; }
                atomicMax(&s_tk[t], mk_key(iou, (unsigned int)(a0 + 768))); }
        }
    }

    if (i0 >= 0) atomicMax(&akeys[a0],       mk_key(b0, (unsigned int)(tbase + i0)));
    if (i1 >= 0) atomicMax(&akeys[a0 + 256], mk_key(b1, (unsigned int)(tbase + i1)));
    if (i2 >= 0) atomicMax(&akeys[a0 + 512], mk_key(b2, (unsigned int)(tbase + i2)));
    if (i3 >= 0) atomicMax(&akeys[a0 + 768], mk_key(b3, (unsigned int)(tbase + i3)));

    __syncthreads();
    if (tid < 64) {
        const unsigned long long tk = s_tk[tid];
        if (tk != 0ull) atomicMax(&tkeys[tbase + tid], tk);
    }
    __syncthreads();   // barrier drains vmcnt: all this block's flushes complete

    // ---- chunk-completion handoff: 16th block of this ac does the cls work ----
    if (tid == 0) {
        __threadfence();
        s_role = (atomicAdd(&done_ac[ac], 1) == TCH - 1);
    }
    __syncthreads();
    if (!s_role) return;

    // ================= completer: focal loss for this ac's 1024 anchors =======
    const int abase = ac * 1024;
    int cnt = 0;
    #pragma unroll
    for (int j = 0; j < 4; ++j) {
        const int i = tid + j * 256;
        // atomicMax(p,0) = coherent device-scope READ (never modifies)
        const unsigned long long k = atomicMax(&akeys[abase + i], 0ull);
        int lab = -1;
        if ((unsigned int)(k >> 32) >= HI_MIN) {
            lab = tlabels[0xFFFFFFFFu - (unsigned int)k];
            ++cnt;
        }
        s_lab[i] = lab;
    }
    for (int o = 32; o > 0; o >>= 1) cnt += __shfl_down(cnt, o);
    const int lane = tid & 63, wid = tid >> 6;
    if (lane == 0) s_cnt[wid] = cnt;
    __syncthreads();
    if (tid == 0) atomicAdd(n_pos, s_cnt[0] + s_cnt[1] + s_cnt[2] + s_cnt[3]);

    float acc = 0.f;
    const int pbase = ac * (1024 * NC);
    for (int e = tid; e < 1024 * NC; e += 256) {
        const int al = e / NC;            // magic-mul div
        const int c  = e - al * NC;
        const float x  = preds[pbase + e];
        const float t  = (s_lab[al] == c) ? 1.f : 0.f;
        const float ax = fabsf(x);
        const float u  = __expf(-ax);
        const float ce = fmaxf(x, 0.f) - x * t + __logf(1.f + u);
        const float p  = (x >= 0.f ? 1.f : u) / (1.f + u);
        const float pt = p * t + (1.f - p) * (1.f - t);
        const float at = 0.25f * t + 0.75f * (1.f - t);
        const float om = 1.f - pt;
        acc += at * om * om * ce;
    }
    for (int o = 32; o > 0; o >>= 1) acc += __shfl_down(acc, o);
    if (lane == 0) s_red[wid] = acc;
    __syncthreads();
    if (tid == 0) {
        atomicAdd(cls_sum, s_red[0] + s_red[1] + s_red[2] + s_red[3]);
        __threadfence();
        s_fin = (atomicAdd(done_global, 1) == ACH - 1);
    }
    __syncthreads();
    if (!s_fin) return;

    // ================= finale (96th completer): regression + combine ==========
    if (tid == 0) {
        s_clsf = atomicAdd(cls_sum, 0.f);   // coherent reads
        s_npf  = atomicAdd(n_pos, 0);
    }
    float s = 0.f, m = 0.f;
    #pragma unroll
    for (int j = 0; j < 4; ++j) {
        const int t = tid + 256 * j;
        const unsigned long long key = atomicMax(&tkeys[t], 0ull);  // coherent read
        if ((unsigned int)(key >> 32) >= HI_MIN) {
            const unsigned int ga = 0xFFFFFFFFu - (unsigned int)key;
            const float4 tb  = tboxes[t];
            const float4 abx = anchors[ga];
            const float4 pb  = bpreds[ga];
            const float bw = tb.z - tb.x, bh = tb.w - tb.y;
            const float bcx = tb.x + 0.5f * bw, bcy = tb.y + 0.5f * bh;
            const float aw = abx.z - abx.x, ah = abx.w - abx.y;
            const float acx = abx.x + 0.5f * aw, acy = abx.y + 0.5f * ah;
            const float tx = (bcx - acx) / aw;
            const float ty = (bcy - acy) / ah;
            const float tw = logf(fmaxf(bw, 1e-8f) / aw);
            const float th = logf(fmaxf(bh, 1e-8f) / ah);
            s += smooth_l1(pb.x - tx) + smooth_l1(pb.y - ty) +
                 smooth_l1(pb.z - tw) + smooth_l1(pb.w - th);
            m += 1.f;
        }
    }
    for (int o = 32; o > 0; o >>= 1) {
        s += __shfl_down(s, o);
        m += __shfl_down(m, o);
    }
    __syncthreads();          // s_red reuse
    if (lane == 0) { s_red[wid] = s; s_red[4 + wid] = m; }
    __syncthreads();
    if (tid == 0) {
        const float rs = s_red[0] + s_red[1] + s_red[2] + s_red[3];
        const float rm = s_red[4] + s_red[5] + s_red[6] + s_red[7];
        const float cls = s_clsf / (float)s_npf;
        const float reg = rs / (fmaxf(rm, 1.f) * 4.f);
        out[0] = cls + reg;
        out[1] = cls;
        out[2] = reg;
    }
}

extern "C" void kernel_launch(void* const* d_in, const int* in_sizes, int n_in,
                              void* d_out, int out_size, void* d_ws, size_t ws_size,
                              hipStream_t stream) {
    const float*  cls_preds = (const float*)d_in[0];
    const float4* bpreds    = (const float4*)d_in[1];
    const float4* anchors   = (const float4*)d_in[2];
    const float4* tboxes    = (const float4*)d_in[3];
    const int*    tlabels   = (const int*)d_in[4];

    char* ws = (char*)d_ws;
    float* cls_sum = (float*)(ws + 0);
    int*   n_pos   = (int*)(ws + 4);
    int*   done_g  = (int*)(ws + 8);
    int*   done_ac = (int*)(ws + 12);
    unsigned long long* tkeys = (unsigned long long*)(ws + 1024);
    unsigned long long* akeys = (unsigned long long*)(ws + 9216);

    // keys need NO zeroing (poison-proof encoding); only the 512-B header does
    hipMemsetAsync(d_ws, 0, 512, stream);

    k_fused<<<dim3(ACH, TCH), 256, 0, stream>>>(
        cls_preds, tlabels, anchors, tboxes, bpreds,
        akeys, tkeys, cls_sum, n_pos, done_g, done_ac, (float*)d_out);
}